// Round 4
// baseline (490.588 us; speedup 1.0000x reference)
//
#include <hip/hip_runtime.h>

#define S_LEN 2048
#define HID   4096
#define NHEAD 32
#define DHEAD 128
#define H3    12288

typedef __attribute__((ext_vector_type(8))) __bf16 bf16x8;
typedef __attribute__((ext_vector_type(4))) __bf16 bf16x4;
typedef __attribute__((ext_vector_type(4))) float  f32x4;

__device__ __forceinline__ void gl_lds16(const void* g, void* l) {
  __builtin_amdgcn_global_load_lds(
      (const __attribute__((address_space(1))) void*)g,
      (__attribute__((address_space(3))) void*)l, 16, 0, 0);
}

// ---------------- fp32 -> bf16 elementwise (hidden states) ----------------
__global__ void cvt_f32_bf16(const float* __restrict__ in, __bf16* __restrict__ out, int n4) {
  int i = blockIdx.x * blockDim.x + threadIdx.x;
  if (i >= n4) return;
  float4 v = ((const float4*)in)[i];
  bf16x4 o;
  o.x = (__bf16)v.x; o.y = (__bf16)v.y; o.z = (__bf16)v.z; o.w = (__bf16)v.w;
  ((bf16x4*)out)[i] = o;
}

// ---------------- fp32 [R][C] -> bf16 [C][R] (weight transpose) ----------------
__global__ void transpose_cvt(const float* __restrict__ in, __bf16* __restrict__ out, int R, int C) {
  __shared__ float t[64][65];
  const int tid = threadIdx.x;
  const int r0 = blockIdx.y * 64, c0 = blockIdx.x * 64;
#pragma unroll
  for (int p = 0; p < 4; ++p) {
    int r = p * 16 + (tid >> 4);
    int c4 = (tid & 15) * 4;
    float4 v = *(const float4*)(in + (size_t)(r0 + r) * C + c0 + c4);
    t[r][c4] = v.x; t[r][c4 + 1] = v.y; t[r][c4 + 2] = v.z; t[r][c4 + 3] = v.w;
  }
  __syncthreads();
#pragma unroll
  for (int p = 0; p < 4; ++p) {
    int c = p * 16 + (tid >> 4);
    int rg = (tid & 15) * 4;
    bf16x4 o;
    o.x = (__bf16)t[rg][c]; o.y = (__bf16)t[rg + 1][c];
    o.z = (__bf16)t[rg + 2][c]; o.w = (__bf16)t[rg + 3][c];
    *(bf16x4*)(out + (size_t)(c0 + c) * R + r0 + rg) = o;
  }
}

// ---------------- RoPE in-place on q,k  [NH][S][D] ----------------
__global__ void rope_kernel(__bf16* __restrict__ q, __bf16* __restrict__ k,
                            const int* __restrict__ pos) {
  int idx = blockIdx.x * 256 + threadIdx.x;   // S*NH*64 items
  int j = idx & 63;
  int hs = idx >> 6;
  int s = hs & (S_LEN - 1);
  float p = (float)pos[s];
  float invf = __expf(-(float)j * (9.210340371976184f / 64.f));  // 10000^(-j/64)
  float a = p * invf;
  float c, sn;
  __sincosf(a, &sn, &c);
  size_t base = (size_t)hs * 128;
  float x1 = (float)q[base + j], x2 = (float)q[base + j + 64];
  q[base + j]      = (__bf16)(x1 * c - x2 * sn);
  q[base + j + 64] = (__bf16)(x2 * c + x1 * sn);
  x1 = (float)k[base + j]; x2 = (float)k[base + j + 64];
  k[base + j]      = (__bf16)(x1 * c - x2 * sn);
  k[base + j + 64] = (__bf16)(x2 * c + x1 * sn);
}

// ---------------- 8-phase-style 256x128 bf16 GEMM, BT input ([N][K]) ----------------
// BK=64, 3-slot LDS ring (144KB), prefetch distance 2, 2 phases/K-tile,
// counted vmcnt(6), raw s_barrier, setprio around MFMA. 512 thr = 8 waves (4M x 2N),
// per-wave 64x64 output. Same verified swizzle/fragment math as the 128^2 kernel.
// EPI 0: qkv epilogue (bias + route to q/k/vt)   EPI 1: dense (bias + fp32 out)
template <int EPI>
__global__ __launch_bounds__(512, 2)
void gemm8(const __bf16* __restrict__ A, const __bf16* __restrict__ BT,
           const float* __restrict__ bias, int K,
           __bf16* __restrict__ outq, __bf16* __restrict__ outk,
           __bf16* __restrict__ outvt, float* __restrict__ outf) {
  const int tid = threadIdx.x, lane = tid & 63, wave = tid >> 6;
  // XCD-chunked bijective block swizzle (grid % 8 == 0); bm fastest within XCD chunk.
  const int nwg = gridDim.x;
  const int q8 = nwg >> 3;
  const int flat = blockIdx.x;
  const int swz = (flat & 7) * q8 + (flat >> 3);
  const int bm = (swz & 7) * 256;     // 8 M-tiles (M=2048)
  const int bn = (swz >> 3) * 128;

  __shared__ char lds[3 * 49152];     // 3 slots x (A 32KB + B 16KB)

  const int K2 = K * 2;
  const int sr = tid >> 3;                               // staging row 0..63
  const int scb = ((tid & 7) * 16) ^ ((sr & 7) << 4);    // swizzled source col-byte (128B row)
  const char* Asrc = (const char*)A + (size_t)(bm + sr) * K2 + scb;
  const char* Bsrc = (const char*)BT + (size_t)(bn + sr) * K2 + scb;

  const int wm = (wave >> 1) * 64;    // 4 M-wave rows
  const int wn = (wave & 1) * 64;     // 2 N-wave cols
  const int cl = lane & 15;
  const int rbase = (lane >> 4) << 2;
  const int khi = (lane >> 4) << 4;

  f32x4 acc[4][4] = {};

  // stage half h of K-tile t into slot t%3 (3 x gl_lds16 per thread per half)
  auto stage_half = [&](int t, int h) {
    const size_t kb = (size_t)t * 128;                 // t*64 elems * 2B
    char* slot = lds + (t % 3) * 49152;
    char* dA = slot + wave * 1024;
    char* dB = slot + 32768 + wave * 1024;
    if (h == 0) {
      gl_lds16(Asrc + kb,                       dA);
      gl_lds16(Asrc + kb + (size_t)64 * K2,     dA + 8192);
      gl_lds16(Bsrc + kb,                       dB);
    } else {
      gl_lds16(Asrc + kb + (size_t)128 * K2,    dA + 16384);
      gl_lds16(Asrc + kb + (size_t)192 * K2,    dA + 24576);
      gl_lds16(Bsrc + kb + (size_t)64 * K2,     dB + 8192);
    }
  };

  const int NT = K >> 6;   // 64
  stage_half(0, 0); stage_half(0, 1);
  stage_half(1, 0); stage_half(1, 1);
  asm volatile("s_waitcnt vmcnt(6)" ::: "memory");
  asm volatile("s_barrier" ::: "memory");

  for (int t = 0; t < NT; ++t) {
    const char* sA = lds + (t % 3) * 49152;
    const char* sB = sA + 32768;
    const bool st = (t + 2) < NT;

    // ---------------- phase 0: m-half 0 ----------------
    {
      bf16x8 af[2][2], bfr[4][2];
#pragma unroll
      for (int mm = 0; mm < 2; ++mm) {
        const int row = wm + mm * 16 + cl;
        const int sw = (row & 7) << 4;
#pragma unroll
        for (int kk = 0; kk < 2; ++kk)
          af[mm][kk] = *(const bf16x8*)(sA + row * 128 + ((kk * 64 + khi) ^ sw));
      }
#pragma unroll
      for (int n = 0; n < 4; ++n) {
        const int row = wn + n * 16 + cl;
        const int sw = (row & 7) << 4;
#pragma unroll
        for (int kk = 0; kk < 2; ++kk)
          bfr[n][kk] = *(const bf16x8*)(sB + row * 128 + ((kk * 64 + khi) ^ sw));
      }
      if (st) stage_half(t + 2, 0);
      asm volatile("s_barrier" ::: "memory");
      asm volatile("s_waitcnt lgkmcnt(0)" ::: "memory");
      __builtin_amdgcn_s_setprio(1);
#pragma unroll
      for (int kk = 0; kk < 2; ++kk)
#pragma unroll
        for (int mm = 0; mm < 2; ++mm)
#pragma unroll
          for (int n = 0; n < 4; ++n)
            acc[mm][n] = __builtin_amdgcn_mfma_f32_16x16x32_bf16(
                af[mm][kk], bfr[n][kk], acc[mm][n], 0, 0, 0);
      __builtin_amdgcn_s_setprio(0);
      asm volatile("s_barrier" ::: "memory");
    }

    // ---------------- phase 1: m-half 1 ----------------
    {
      bf16x8 af[2][2], bfr[4][2];
#pragma unroll
      for (int mm = 0; mm < 2; ++mm) {
        const int row = wm + (2 + mm) * 16 + cl;
        const int sw = (row & 7) << 4;
#pragma unroll
        for (int kk = 0; kk < 2; ++kk)
          af[mm][kk] = *(const bf16x8*)(sA + row * 128 + ((kk * 64 + khi) ^ sw));
      }
#pragma unroll
      for (int n = 0; n < 4; ++n) {
        const int row = wn + n * 16 + cl;
        const int sw = (row & 7) << 4;
#pragma unroll
        for (int kk = 0; kk < 2; ++kk)
          bfr[n][kk] = *(const bf16x8*)(sB + row * 128 + ((kk * 64 + khi) ^ sw));
      }
      if (st) stage_half(t + 2, 1);
      if (t < NT - 1) {
        if (st) asm volatile("s_waitcnt vmcnt(6)" ::: "memory");
        else    asm volatile("s_waitcnt vmcnt(0)" ::: "memory");
      }
      asm volatile("s_barrier" ::: "memory");
      asm volatile("s_waitcnt lgkmcnt(0)" ::: "memory");
      __builtin_amdgcn_s_setprio(1);
#pragma unroll
      for (int kk = 0; kk < 2; ++kk)
#pragma unroll
        for (int mm = 0; mm < 2; ++mm)
#pragma unroll
          for (int n = 0; n < 4; ++n)
            acc[2 + mm][n] = __builtin_amdgcn_mfma_f32_16x16x32_bf16(
                af[mm][kk], bfr[n][kk], acc[2 + mm][n], 0, 0, 0);
      __builtin_amdgcn_s_setprio(0);
      asm volatile("s_barrier" ::: "memory");
    }
  }

  if (EPI == 0) {
    const int route = (bn >> 7) % 3;   // 0=q 1=k 2=v (tiles align: 384 = 3*128)
    const int head = bn / 384;
#pragma unroll
    for (int n = 0; n < 4; ++n) {
      const int d = wn + n * 16 + cl;            // 0..127 within block
      const float bv = bias[bn + d];
#pragma unroll
      for (int m = 0; m < 4; ++m) {
        const int srow = bm + wm + m * 16 + rbase;
        if (route == 2) {
          bf16x4 o;
          o.x = (__bf16)(acc[m][n][0] + bv);
          o.y = (__bf16)(acc[m][n][1] + bv);
          o.z = (__bf16)(acc[m][n][2] + bv);
          o.w = (__bf16)(acc[m][n][3] + bv);
          *(bf16x4*)(outvt + ((size_t)head * 128 + d) * S_LEN + srow) = o;
        } else {
          __bf16* dst = (route == 0 ? outq : outk) + (size_t)head * S_LEN * 128;
#pragma unroll
          for (int r = 0; r < 4; ++r)
            dst[(size_t)(srow + r) * 128 + d] = (__bf16)(acc[m][n][r] + bv);
        }
      }
    }
  } else {
#pragma unroll
    for (int n = 0; n < 4; ++n) {
      const int col = bn + wn + n * 16 + cl;
      const float bv = bias[col];
#pragma unroll
      for (int m = 0; m < 4; ++m) {
        const int srow = bm + wm + m * 16 + rbase;
#pragma unroll
        for (int r = 0; r < 4; ++r)
          outf[(size_t)(srow + r) * HID + col] = acc[m][n][r] + bv;
      }
    }
  }
}

// ---------------- flash attention (causal), load-balanced paired q-tiles ----------------
__global__ __launch_bounds__(256, 2)
void attn_kernel(const __bf16* __restrict__ q, const __bf16* __restrict__ k,
                 const __bf16* __restrict__ vt, __bf16* __restrict__ ctx) {
  const int p = blockIdx.x, h = blockIdx.y;
  const int tid = threadIdx.x, lane = tid & 63, wave = tid >> 6;
  __shared__ __bf16 Ks[64 * 128];     // [kv][d]   256B rows
  __shared__ __bf16 Vs[128 * 64];     // [d][kv]   128B rows
  __shared__ __bf16 Ps[4][16 * 64];   // per-wave P (16 q-rows x 64 kv), 128B rows
  char* Kb = (char*)Ks;
  char* Vb = (char*)Vs;
  char* Pb = (char*)(Ps[wave]);

  const __bf16* qh = q + (size_t)h * S_LEN * 128;
  const __bf16* kh = k + (size_t)h * S_LEN * 128;
  const __bf16* vh = vt + (size_t)h * 128 * S_LEN;

  const int cl = lane & 15, rbase = (lane >> 4) << 2;

  const int krow = tid >> 4, kcol = (tid & 15) * 16;
  const int kcs = kcol ^ ((krow & 7) << 4);
  const int vrow = tid >> 3, vcol = (tid & 7) * 16;
  const int vcs = vcol ^ ((vrow & 7) << 4);

  for (int half = 0; half < 2; ++half) {
    const int qt = half ? (31 - p) : p;      // q-tile index (64 rows)
    const int qrow0 = qt * 64 + wave * 16;   // this wave's first q-row

    bf16x8 qf[4];
#pragma unroll
    for (int kk = 0; kk < 4; ++kk)
      qf[kk] = *(const bf16x8*)(qh + (size_t)(qrow0 + cl) * 128 + kk * 32 + ((lane >> 4) << 3));

    f32x4 oacc[8] = {};
    float mrow[4], lrow[4];
#pragma unroll
    for (int r = 0; r < 4; ++r) { mrow[r] = -1e30f; lrow[r] = 0.f; }

    for (int j = 0; j <= qt; ++j) {
      {
        const char* src = (const char*)(kh + (size_t)(j * 64 + krow) * 128) + kcs;
        char* dst = Kb + wave * 1024;
#pragma unroll
        for (int i = 0; i < 4; ++i)
          gl_lds16(src + (size_t)i * 16 * 256, dst + i * 4096);
      }
      {
        const char* src = (const char*)(vh + (size_t)vrow * S_LEN + j * 64) + vcs;
        char* dst = Vb + wave * 1024;
#pragma unroll
        for (int i = 0; i < 4; ++i)
          gl_lds16(src + (size_t)i * 32 * (S_LEN * 2), dst + i * 4096);
      }
      __syncthreads();

      // ---- QK^T: 16 q-rows x 64 kv ----
      f32x4 sacc[4] = {};
#pragma unroll
      for (int kk = 0; kk < 4; ++kk) {
        bf16x8 bk[4];
#pragma unroll
        for (int n = 0; n < 4; ++n) {
          int row = n * 16 + cl;
          int cb = (kk * 64 + ((lane >> 4) << 4)) ^ ((row & 7) << 4);
          bk[n] = *(const bf16x8*)(Kb + row * 256 + cb);
        }
#pragma unroll
        for (int n = 0; n < 4; ++n)
          sacc[n] = __builtin_amdgcn_mfma_f32_16x16x32_bf16(qf[kk], bk[n], sacc[n], 0, 0, 0);
      }

      // ---- online softmax ----
      float pmax[4];
#pragma unroll
      for (int r = 0; r < 4; ++r) pmax[r] = -1e30f;
      if (j == qt) {   // diagonal tile: causal mask (wave-uniform branch)
#pragma unroll
        for (int n = 0; n < 4; ++n) {
          const int col = n * 16 + cl;
#pragma unroll
          for (int r = 0; r < 4; ++r) {
            const int row = wave * 16 + rbase + r;
            float sv = sacc[n][r] * 0.08838834764831845f;
            sv = (col > row) ? -1e30f : sv;
            sacc[n][r] = sv;
            pmax[r] = fmaxf(pmax[r], sv);
          }
        }
      } else {
#pragma unroll
        for (int n = 0; n < 4; ++n)
#pragma unroll
          for (int r = 0; r < 4; ++r) {
            float sv = sacc[n][r] * 0.08838834764831845f;
            sacc[n][r] = sv;
            pmax[r] = fmaxf(pmax[r], sv);
          }
      }
#pragma unroll
      for (int xm = 1; xm < 16; xm <<= 1)
#pragma unroll
        for (int r = 0; r < 4; ++r)
          pmax[r] = fmaxf(pmax[r], __shfl_xor(pmax[r], xm, 64));
#pragma unroll
      for (int r = 0; r < 4; ++r) {
        const float mnew = fmaxf(mrow[r], pmax[r]);
        const float alpha = __expf(mrow[r] - mnew);
        mrow[r] = mnew;
        float psum = 0.f;
#pragma unroll
        for (int n = 0; n < 4; ++n) {
          float pe = __expf(sacc[n][r] - mnew);
          sacc[n][r] = pe;
          psum += pe;
        }
#pragma unroll
        for (int xm = 1; xm < 16; xm <<= 1)
          psum += __shfl_xor(psum, xm, 64);
        lrow[r] = lrow[r] * alpha + psum;
#pragma unroll
        for (int nd = 0; nd < 8; ++nd)
          oacc[nd][r] *= alpha;
      }

      // ---- P -> LDS (bf16, swizzled) ----
#pragma unroll
      for (int n = 0; n < 4; ++n) {
        const int colb = (n * 16 + cl) * 2;
#pragma unroll
        for (int r = 0; r < 4; ++r) {
          const int row = rbase + r;
          *(__bf16*)(Pb + row * 128 + (colb ^ ((row & 7) << 4))) = (__bf16)sacc[n][r];
        }
      }

      // ---- PV ----
#pragma unroll
      for (int kk = 0; kk < 2; ++kk) {
        bf16x8 pa, bv[8];
        {
          int row = cl;
          int cb = (kk * 64 + ((lane >> 4) << 4)) ^ ((row & 7) << 4);
          pa = *(const bf16x8*)(Pb + row * 128 + cb);
        }
#pragma unroll
        for (int nd = 0; nd < 8; ++nd) {
          int row = nd * 16 + cl;
          int cb = (kk * 64 + ((lane >> 4) << 4)) ^ ((row & 7) << 4);
          bv[nd] = *(const bf16x8*)(Vb + row * 128 + cb);
        }
#pragma unroll
        for (int nd = 0; nd < 8; ++nd)
          oacc[nd] = __builtin_amdgcn_mfma_f32_16x16x32_bf16(pa, bv[nd], oacc[nd], 0, 0, 0);
      }
      __syncthreads();
    }

    // ---- epilogue for this q-tile ----
#pragma unroll
    for (int nd = 0; nd < 8; ++nd) {
      const int d = nd * 16 + cl;
#pragma unroll
      for (int r = 0; r < 4; ++r) {
        const int srow = qrow0 + rbase + r;
        ctx[(size_t)srow * HID + h * 128 + d] = (__bf16)(oacc[nd][r] / lrow[r]);
      }
    }
  }
}

extern "C" void kernel_launch(void* const* d_in, const int* in_sizes, int n_in,
                              void* d_out, int out_size, void* d_ws, size_t ws_size,
                              hipStream_t stream) {
  const float* hs = (const float*)d_in[0];
  const int* pos = (const int*)d_in[1];
  const float* wqkv = (const float*)d_in[3];
  const float* bqkv = (const float*)d_in[4];
  const float* wd = (const float*)d_in[5];
  const float* bd = (const float*)d_in[6];
  float* out = (float*)d_out;

  char* ws = (char*)d_ws;
  const size_t MB = 1024ull * 1024ull;
  if (ws_size < 160 * MB) return;   // need 160MB scratch
  __bf16* wT  = (__bf16*)(ws);             // 96MB: wqkv^T bf16 [12288][4096]; later wdense^T
  __bf16* xb  = (__bf16*)(ws + 96 * MB);   // 16MB: x bf16; later ctx bf16
  __bf16* qb_ = (__bf16*)(ws + 112 * MB);  // 16MB: q [NH][S][D]
  __bf16* kb_ = (__bf16*)(ws + 128 * MB);  // 16MB: k [NH][S][D]
  __bf16* vtb = (__bf16*)(ws + 144 * MB);  // 16MB: v^T [NH][D][S]

  cvt_f32_bf16<<<8192, 256, 0, stream>>>(hs, xb, 2097152);
  transpose_cvt<<<dim3(192, 64), 256, 0, stream>>>(wqkv, wT, 4096, 12288);
  gemm8<0><<<768, 512, 0, stream>>>(xb, wT, bqkv, 4096, qb_, kb_, vtb, nullptr);
  rope_kernel<<<16384, 256, 0, stream>>>(qb_, kb_, pos);
  transpose_cvt<<<dim3(64, 64), 256, 0, stream>>>(wd, wT, 4096, 4096);
  attn_kernel<<<dim3(16, 32), 256, 0, stream>>>(qb_, kb_, vtb, xb);
  gemm8<1><<<256, 512, 0, stream>>>(xb, wT, bd, 4096, nullptr, nullptr, nullptr, out);
}